// Round 10
// baseline (854.019 us; speedup 1.0000x reference)
//
#include <hip/hip_runtime.h>
#include <hip/hip_bf16.h>

// RNN: B=4096, T=1024, H=40, K=41. fp32 compute & state (dtype autodetected).
// Round-20: cheap-remat via workspace-packed fp32 weights.
// R19 post-mortem: zero-cost wave fences changed NOTHING (816->823) ->
// barrier drain was not the stall. absmax = 2^-11 exactly => DATASET IS BF16:
// FETCH 16.5MB = 8.4 input + 8.4 output-RMW; weights live in L2. So every
// remat'd weight f2 on the hot path = 2x global_load_ushort + ~3 shift/pack
// VALU. At ~40 f2/lane-step: ~80 loads + ~120 VALU of remat tax per
// wave-step -- the 1913 cyc/step. Rounds 10-19 all paid this; residency is
// unwinnable (7 allocator fights), so make reloads nearly free instead:
//   pack_weights kernel (1 block, once per launch): converts ALL weights to
//   fp32 (exact for bf16 -> numerics unchanged) into d_ws, laid out
//   per-lane: ws[lane*88 .. +87] = {s0[20], s1[20], s2[20], s3[20],
//   wu0,wu1,wu2,ba0,ba1,ba2,bb2,bb3} -- exactly the slices R19's loader
//   computed. Main kernel loads each 20-float slot as 5x dwordx4 from ONE
//   base with immediate offsets: remat = 20 loads + 0 addr VALU per step.
// Structure/math: identical to R19 (single-wave blocks, grid 4096, kh-split
// + DPP pair reduce, pk_fma, WFENCE, 4 slots). absmax-stable.

#define B_SZ 4096
#define T_SZ 1024
#define HID  40
#define WSTRIDE 88   // floats per lane slice in ws (352 B, 16B-aligned)

typedef unsigned short u16;
typedef unsigned int   u32;
typedef float f2 __attribute__((ext_vector_type(2)));
typedef float f4 __attribute__((ext_vector_type(4)));

// Zero-cost single-wave "barrier": hardware processes a wave's LDS ops in
// program order; only forbid COMPILER reordering.
#define WFENCE() do {                      \
    asm volatile("" ::: "memory");         \
    __builtin_amdgcn_wave_barrier();       \
    asm volatile("" ::: "memory");         \
  } while (0)

__device__ __forceinline__ float bf2f(u16 v) {
  union { u32 u; float f; } c; c.u = ((u32)v) << 16; return c.f;
}

// Proven rounds 3-19: true-bf16 weights all have |w| <= 1/sqrt(41) ~ 0.156;
// fp32 data read as bf16 halfwords exceeds 0.2 with P ~ 1-1e-10.
__device__ __forceinline__ bool detect_bf16(const void* w) {
  const u16* p = (const u16*)w;
  bool bf = true;
  for (int i = 0; i < 64; ++i) {
    float f = bf2f(p[i]);
    if (!(fabsf(f) <= 0.2f)) bf = false;
  }
  return bf;
}

__device__ __forceinline__ float ldgr(bool bf, const void* p, long i) {
  return bf ? bf2f(((const u16*)p)[i]) : ((const float*)p)[i];
}

// Partner value from lane^1 (quad_perm [1,0,3,2]). VALU pipe, no LDS.
__device__ __forceinline__ float pair_other(float x) {
  return __int_as_float(__builtin_amdgcn_update_dpp(
      0, __float_as_int(x), 0xB1, 0xF, 0xF, true));
}

// ---- Pack kernel: replicate R19's per-lane slot logic, fp32 into ws ----
__global__ __launch_bounds__(64)
void pack_weights(const void* __restrict__ h2h_w1, const void* __restrict__ h2h_b1,
                  const void* __restrict__ h2h_w2, const void* __restrict__ h2h_b2,
                  const void* __restrict__ h2o_w1, const void* __restrict__ h2o_b1,
                  const void* __restrict__ h2o_w2, const void* __restrict__ h2o_b2,
                  float* __restrict__ ws) {
  const bool bf  = detect_bf16(h2h_w1);
  const int lane = threadIdx.x;       // 0..63
  const int kh   = lane & 1;
  const int w    = lane >> 1;
  const int koff = kh * 20;

  const bool hh01 = (2 * w < HID);
  const void* p01 = hh01 ? h2h_w1 : h2o_w1;
  const long  jr0 = hh01 ? 2 * w : 2 * w - HID;
  const bool  s2A = (w >= 16);
  const void* p2  = s2A ? h2o_w1 : h2h_w2;
  const long  o2  = s2A ? ((long)(8 + w) * 41 + 1 + koff) : ((long)w * HID + koff);
  const bool  isOut = (w == 24);
  const void* p3  = isOut ? h2o_w2 : h2h_w2;
  const long  o3  = isOut ? (long)koff : ((long)(16 + (w < 24 ? w : 0)) * HID + koff);

  float* dst = ws + (long)lane * WSTRIDE;
  for (int i = 0; i < 20; ++i) {
    dst[i]      = ldgr(bf, p01, jr0 * 41 + 1 + koff + i);
    dst[20 + i] = ldgr(bf, p01, (jr0 + 1) * 41 + 1 + koff + i);
    dst[40 + i] = ldgr(bf, p2, o2 + i);
    dst[60 + i] = ldgr(bf, p3, o3 + i);
  }
  float wu0 = 0, wu1 = 0, wu2 = 0, ba0 = 0, ba1 = 0, ba2 = 0, bb2 = 0, bb3 = 0;
  if (kh == 0) {
    const void* b1p = hh01 ? h2h_b1 : h2o_b1;
    wu0 = ldgr(bf, p01, jr0 * 41);
    wu1 = ldgr(bf, p01, (jr0 + 1) * 41);
    ba0 = ldgr(bf, b1p, jr0);
    ba1 = ldgr(bf, b1p, jr0 + 1);
    if (s2A) { wu2 = ldgr(bf, h2o_w1, (long)(8 + w) * 41); ba2 = ldgr(bf, h2o_b1, 8 + w); }
    else     { bb2 = ldgr(bf, h2h_b2, w); }
    if (isOut)       bb3 = ldgr(bf, h2o_b2, 0);
    else if (w < 24) bb3 = ldgr(bf, h2h_b2, 16 + w);
  }
  dst[80] = wu0; dst[81] = wu1; dst[82] = wu2; dst[83] = ba0;
  dst[84] = ba1; dst[85] = ba2; dst[86] = bb2; dst[87] = bb3;
}

template <bool BF>
__global__ __launch_bounds__(64, 2)
void rnn_kernel(const void* __restrict__ inp, const void* __restrict__ h2h_w1,
                const float* __restrict__ ws, void* __restrict__ out) {
  __shared__ __align__(16) float sH[44];  // hidden state h[0..39]
  __shared__ __align__(16) float sA[84];  // L1 acts: a-rows [0..39], o-rows [40..79]

  if (detect_bf16(h2h_w1) != BF) return;  // wrong-dtype instantiation exits

  const int lane = threadIdx.x & 63;
  const int kh   = lane & 1;          // K-half: 0 -> u + k0..19, 1 -> k20..39
  const int w    = lane >> 1;         // worker 0..31
  const int koff = kh * 20;
  const bool s2A   = (w >= 16);
  const bool isOut = (w == 24);

  // ---- Weights: per-lane packed fp32 slice; slots load as 5x dwordx4 each
  //      from ONE base + immediate offsets (remat = 20 loads, 0 addr VALU).
  const f4* wq = (const f4*)(ws + (long)lane * WSTRIDE);
  f4 s0q[5], s1q[5], s2q[5], s3q[5];
#pragma unroll
  for (int i = 0; i < 5; ++i) {
    s0q[i] = wq[i];
    s1q[i] = wq[5 + i];
    s2q[i] = wq[10 + i];
    s3q[i] = wq[15 + i];
  }
  const f2* s0 = (const f2*)s0q;
  const f2* s1 = (const f2*)s1q;
  const f2* s2 = (const f2*)s2q;
  const f2* s3 = (const f2*)s3q;
  const float* wsc = ws + (long)lane * WSTRIDE + 80;
  const float wu0 = wsc[0], wu1 = wsc[1], wu2 = wsc[2], ba0 = wsc[3];
  const float ba1 = wsc[4], ba2 = wsc[5], bb2 = wsc[6], bb3 = wsc[7];

  for (int i = lane; i < 44; i += 64) sH[i] = 0.f;
  WFENCE();   // single wave: zeroing writes ordered before first reads

  const long base = (long)blockIdx.x * T_SZ;   // 1 el per block
  float u_cur = BF ? bf2f(((const u16*)inp)[base]) : ((const float*)inp)[base];

  const f4* hp = (const f4*)(&sH[koff]);                     // broadcast
  const f4* ap = (const f4*)(&sA[isOut ? 40 + koff : koff]); // broadcast (2 addrs)
  const bool wrA2 = s2A && (kh == 0);
  const bool wr2  = (!s2A) && (kh == 0);        // w<16: new h[w]
  const bool wr3  = (w < 24) && (kh == 0);      // new h[16+w]
  const bool wrY  = isOut && (kh == 0);

  for (int t = 0; t < T_SZ; ++t) {
    const float u_nxt = (t + 1 < T_SZ)
        ? (BF ? bf2f(((const u16*)inp)[base + t + 1]) : ((const float*)inp)[base + t + 1])
        : 0.f;

    // ---------- Phase A: L1 rows (slots 0,1,2) vs state ----------
    {
      f4 hv4[5];
#pragma unroll
      for (int i = 0; i < 5; ++i) hv4[i] = hp[i];
      const f2* hv = (const f2*)hv4;
      f2 a0 = {0.f, 0.f}, a1 = {0.f, 0.f}, a2 = {0.f, 0.f};
#pragma unroll
      for (int i = 0; i < 10; ++i) {
        a0 = hv[i] * s0[i] + a0;
        a1 = hv[i] * s1[i] + a1;
        a2 = hv[i] * s2[i] + a2;   // garbage for w<16 (not written)
      }
      const float v0 = fmaf(u_cur, wu0, ba0) + a0.x + a0.y;
      const float v1 = fmaf(u_cur, wu1, ba1) + a1.x + a1.y;
      const float v2 = fmaf(u_cur, wu2, ba2) + a2.x + a2.y;
      const float t0 = v0 + pair_other(v0);
      const float t1 = v1 + pair_other(v1);
      const float t2 = v2 + pair_other(v2);
      if (kh == 0) {
        f2 act01;
        act01.x = fmaxf(t0, 0.01f * t0);
        act01.y = fmaxf(t1, 0.01f * t1);
        *(f2*)(&sA[2 * w]) = act01;            // b64, 2-way bank (free)
      }
      if (wrA2) sA[48 + w] = fmaxf(t2, 0.01f * t2);   // o-acts rows 64..79
    }
    WFENCE();   // in-wave DS order: acts written before phase-B reads

    // ---------- Phase B: L2 rows + output (slots 2,3) vs acts ----------
    {
      f4 av4[5];
#pragma unroll
      for (int i = 0; i < 5; ++i) av4[i] = ap[i];
      const f2* av = (const f2*)av4;
      f2 b2 = {0.f, 0.f}, b3 = {0.f, 0.f};
#pragma unroll
      for (int i = 0; i < 10; ++i) {
        b2 = av[i] * s2[i] + b2;   // garbage for w>=16 (not written)
        b3 = av[i] * s3[i] + b3;   // garbage for w>24 (not written)
      }
      const float v2 = bb2 + b2.x + b2.y;
      const float v3 = bb3 + b3.x + b3.y;
      const float t2 = v2 + pair_other(v2);
      const float t3 = v3 + pair_other(v3);
      if (wr2) sH[w] = t2;                     // new h[0..15]
      if (wr3) sH[16 + w] = t3;                // new h[16..39]
      if (wrY) {                               // y(t)
        if (BF) ((__hip_bfloat16*)out)[base + t] = __float2bfloat16(t3);
        else    ((float*)out)[base + t] = t3;
      }
    }
    WFENCE();   // acts consumed before next step's phase-A overwrites

    u_cur = u_nxt;
  }
}

extern "C" void kernel_launch(void* const* d_in, const int* in_sizes, int n_in,
                              void* d_out, int out_size, void* d_ws, size_t ws_size,
                              hipStream_t stream) {
  (void)in_sizes; (void)n_in; (void)out_size;
  if (ws_size < (size_t)(64 * WSTRIDE * sizeof(float))) return;  // need 22.5 KB
  float* ws = (float*)d_ws;
  pack_weights<<<dim3(1), dim3(64), 0, stream>>>(
      d_in[1], d_in[2], d_in[3], d_in[4],
      d_in[5], d_in[6], d_in[7], d_in[8], ws);
  rnn_kernel<false><<<dim3(B_SZ), dim3(64), 0, stream>>>(
      d_in[0], d_in[1], ws, d_out);
  rnn_kernel<true><<<dim3(B_SZ), dim3(64), 0, stream>>>(
      d_in[0], d_in[1], ws, d_out);
}